// Round 7
// baseline (25.470 us; speedup 1.0000x reference)
//
#include <hip/hip_runtime.h>

// ROI adaptive max pool 7x7 over top-left h[n] x w[n] of 14x14 planes.
// N=512, C=256. Bin spans 1..3 per dim -> branchless 3-point max per dim.
//
// Round-7 experiment: R6 pipelined persistent structure, but GAPLESS staging.
// R6's row-skip cut read bytes 25% but fragmented the read stream (0..384B
// hole per 784B plane); effective BW dropped 4.9 -> 4.2 TB/s. This variant
// reads every plane fully (V=49, packed LDS stride 49 float4) so the global
// stream is perfectly contiguous. Discriminates BW~6.3 (gaps were the cost,
// expect ~21us) vs BW~5.0 (bytes were the cost, expect ~26us -> R6 roofline).

constexpr int N_    = 512;
constexpr int C_    = 256;
constexpr int WMAX  = 14;
constexpr int OUT   = 7;
constexpr int P     = 16;                 // planes per tile
constexpr int NTILE = (N_ * C_) / P;      // 8192
constexpr int G     = 1024;               // blocks (4/CU, all resident)
constexpr int T     = NTILE / G;          // 8 tiles per block
constexpr int PS4   = 49;                 // LDS plane stride in float4 (packed)
constexpr int PSF   = PS4 * 4;            // 196 floats (196 % 32 = 4 stagger)
constexpr int NOUT  = P * OUT * OUT;      // 784 outputs per tile

typedef const __attribute__((address_space(1))) unsigned int* gas_u32;
typedef __attribute__((address_space(3))) unsigned int* las_u32;

template<int LW>
__device__ __forceinline__ void hpool(const float (&vm)[WMAX], float (&o)[OUT]) {
    #pragma unroll
    for (int j = 0; j < OUT; ++j) {
        int c1 = (j * LW) / 7;
        int c3 = ((j + 1) * LW + 6) / 7 - 1;
        int c2 = (c1 + 1 < c3) ? c1 + 1 : c3;
        o[j] = fmaxf(fmaxf(vm[c1], vm[c2]), vm[c3]);
    }
}

__global__ __launch_bounds__(256) void roipool_kernel(
    const float* __restrict__ rois,
    const int*   __restrict__ h,
    const int*   __restrict__ w,
    float*       __restrict__ out)
{
    __shared__ float4 buf[2][P * PS4];    // 2 x 12544 B
    __shared__ float  ostage[NOUT];       // 3136 B

    const int tid  = threadIdx.x;
    const int lane = tid & 63;
    const int wv   = tid >> 6;
    const int blk  = blockIdx.x;

    // prefetch all tile ROI sizes (block-uniform -> scalar loads)
    int LH[T], LWv[T];
    #pragma unroll
    for (int k = 0; k < T; ++k) {
        int n = (blk >> 4) + 64 * k;      // (blk + k*G) / 16
        LH[k]  = h[n];
        LWv[k] = w[n];
    }

    // gapless stage: each wave stages 4 full planes (49 lanes x 16B each);
    // global addresses cover the tile contiguously, zero holes.
    auto stage = [&](int k, int b) {
        const float4* src = (const float4*)rois + (size_t)(blk + k * G) * (P * 49);
        #pragma unroll
        for (int s = 0; s < 4; ++s) {
            const int p = 4 * wv + s;
            if (lane < 49) {
                __builtin_amdgcn_global_load_lds(
                    (gas_u32)(src + p * 49 + lane),
                    (las_u32)(&buf[b][p * PS4]),
                    16, 0, 0);
            }
        }
    };

    stage(0, 0);

    #pragma unroll
    for (int t = 0; t < T; ++t) {
        if (t + 1 < T) stage(t + 1, (t + 1) & 1);

        // per-wave vmcnt: stage = 4 ops, store = 1 op.
        // t==0: after stage(0)x4 comes stage(1)x4 -> wait 4.
        // middle: stage(t)x4, store(t-1), stage(t+1)x4 -> wait 5.
        // last: stage(T-1)x4, store(T-2) -> wait 1.
        if (t == 0)          asm volatile("s_waitcnt vmcnt(4)" ::: "memory");
        else if (t == T - 1) asm volatile("s_waitcnt vmcnt(1)" ::: "memory");
        else                 asm volatile("s_waitcnt vmcnt(5)" ::: "memory");
        __builtin_amdgcn_s_barrier();
        asm volatile("" ::: "memory");    // keep LDS reads below the barrier

        if (tid < P * OUT) {              // 112 threads: one (plane, out-row) each
            const int p  = tid / 7;
            const int i  = tid - p * 7;
            const int Lh = LH[t];

            int th = i * Lh;
            int r1 = th / 7;
            int r3 = (th + Lh + 6) / 7 - 1;
            int r2 = min(r1 + 1, r3);

            const float*  pb = (const float*)&buf[t & 1][0] + p * PSF;
            const float2* a  = (const float2*)(pb + r1 * WMAX);
            const float2* bb = (const float2*)(pb + r2 * WMAX);
            const float2* c  = (const float2*)(pb + r3 * WMAX);

            float vm[WMAX];
            #pragma unroll
            for (int kk = 0; kk < 7; ++kk) {
                float2 x = a[kk], y = bb[kk], z = c[kk];
                vm[2 * kk]     = fmaxf(fmaxf(x.x, y.x), z.x);
                vm[2 * kk + 1] = fmaxf(fmaxf(x.y, y.y), z.y);
            }

            float o[OUT];
            switch (LWv[t]) {
                case  7: hpool< 7>(vm, o); break;
                case  8: hpool< 8>(vm, o); break;
                case  9: hpool< 9>(vm, o); break;
                case 10: hpool<10>(vm, o); break;
                case 11: hpool<11>(vm, o); break;
                case 12: hpool<12>(vm, o); break;
                case 13: hpool<13>(vm, o); break;
                default: hpool<14>(vm, o); break;
            }

            float* os = ostage + tid * OUT;
            #pragma unroll
            for (int j = 0; j < OUT; ++j) os[j] = o[j];
        }

        asm volatile("s_waitcnt lgkmcnt(0)" ::: "memory");
        __builtin_amdgcn_s_barrier();
        asm volatile("" ::: "memory");    // keep ostage reads below the barrier

        if (tid < NOUT / 4) {             // coalesced float4 writeback
            ((float4*)out)[(size_t)(blk + t * G) * (NOUT / 4) + tid] =
                ((const float4*)ostage)[tid];
        }
    }
}

extern "C" void kernel_launch(void* const* d_in, const int* in_sizes, int n_in,
                              void* d_out, int out_size, void* d_ws, size_t ws_size,
                              hipStream_t stream)
{
    const float* rois = (const float*)d_in[0];
    const int*   h    = (const int*)d_in[1];
    const int*   w    = (const int*)d_in[2];
    float*       out  = (float*)d_out;

    roipool_kernel<<<G, 256, 0, stream>>>(rois, h, w, out);
}

// Round 9
// 24.404 us; speedup vs baseline: 1.0437x; 1.0437x over previous
//
#include <hip/hip_runtime.h>

// ROI adaptive max pool 7x7 over top-left h[n] x w[n] of 14x14 planes.
// N=512, C=256. Bin spans 1..3 per dim -> branchless 3-point max per dim.
//
// Round-9 = Round-8 with the packed-stride bug fixed.
// R8 bug: compute used plane stride 14*Lh+2 floats, but staging packs planes
// at 4V floats where V=(7*Lh+1)>>1; these differ by 2 for EVEN Lh -> all
// planes p>=1 misread in even-Lh images. Fix: PS = 4*V.
//
// Structure (from R8): pipelined persistent blocks, lane-full flat staging.
//   flat f in [0,16V): global f4 = (f/V)*49 + f%V (magic div, exact f<784),
//   64 contiguous lanes per global_load_lds, packed LDS copy, tail lanes
//   clamped (write LDS slots >= F only). Counted vmcnt, dbuf, raw barriers.

constexpr int N_    = 512;
constexpr int C_    = 256;
constexpr int WMAX  = 14;
constexpr int OUT   = 7;
constexpr int P     = 16;                 // planes per tile
constexpr int NTILE = (N_ * C_) / P;      // 8192
constexpr int G     = 1024;               // blocks (4/CU, all resident)
constexpr int T     = NTILE / G;          // 8 tiles per block
constexpr int NOUT  = P * OUT * OUT;      // 784 outputs per tile

typedef const __attribute__((address_space(1))) unsigned int* gas_u32;
typedef __attribute__((address_space(3))) unsigned int* las_u32;

template<int LW>
__device__ __forceinline__ void hpool(const float (&vm)[WMAX], float (&o)[OUT]) {
    #pragma unroll
    for (int j = 0; j < OUT; ++j) {
        int c1 = (j * LW) / 7;
        int c3 = ((j + 1) * LW + 6) / 7 - 1;
        int c2 = (c1 + 1 < c3) ? c1 + 1 : c3;
        o[j] = fmaxf(fmaxf(vm[c1], vm[c2]), vm[c3]);
    }
}

__global__ __launch_bounds__(256) void roipool_kernel(
    const float* __restrict__ rois,
    const int*   __restrict__ h,
    const int*   __restrict__ w,
    float*       __restrict__ out)
{
    // 1024 f4 per buffer: slots [16V, 1024) absorb clamped-lane writes.
    __shared__ float4 buf[2][1024];       // 2 x 16384 B
    __shared__ float  ostage[NOUT];       // 3136 B

    const int tid  = threadIdx.x;
    const int lane = tid & 63;
    const int wv   = tid >> 6;
    const int blk  = blockIdx.x;

    // block-uniform ROI sizes for all T tiles (scalar loads)
    int LH[T], LWv[T];
    #pragma unroll
    for (int k = 0; k < T; ++k) {
        int n = (blk >> 4) + 64 * k;      // (blk + k*G) / 16
        LH[k]  = h[n];
        LWv[k] = w[n];
    }

    // lane-full flat stage of the used (row-skipped) region of 16 planes.
    auto stage = [&](int k, int b) {
        const int V = (7 * LH[k] + 1) >> 1;        // used f4 per plane (25..49)
        const int F = 16 * V;                      // used f4 per tile (400..784)
        const int M = (1048576 + V - 1) / V;       // ceil(2^20/V): exact /V for f<784
        const float4* src = (const float4*)rois + (size_t)(blk + k * G) * (P * 49);
        #pragma unroll
        for (int s = 0; s < 4; ++s) {
            int f = s * 256 + wv * 64 + lane;      // flat used-f4 index
            f = min(f, F - 1);                     // clamp tail lanes (dup reads,
                                                   // writes land in LDS tail)
            int pl = (int)(((unsigned)f * (unsigned)M) >> 20);   // f / V
            int g  = pl * 49 + (f - pl * V);                     // global f4 index
            __builtin_amdgcn_global_load_lds(
                (gas_u32)(src + g),
                (las_u32)((float4*)&buf[b][0] + (s * 256 + wv * 64)),
                16, 0, 0);
        }
    };

    stage(0, 0);

    #pragma unroll
    for (int t = 0; t < T; ++t) {
        if (t + 1 < T) stage(t + 1, (t + 1) & 1);

        // per-wave outstanding VMEM: stage = 4 ops (always), store = 1 op.
        // t==0: stage(0)x4 then stage(1)x4 -> wait 4.
        // middle: stage(t)x4, store(t-1), stage(t+1)x4 -> wait 5.
        // last: stage(T-1)x4, store(T-2) -> wait 1.
        if (t == 0)          asm volatile("s_waitcnt vmcnt(4)" ::: "memory");
        else if (t == T - 1) asm volatile("s_waitcnt vmcnt(1)" ::: "memory");
        else                 asm volatile("s_waitcnt vmcnt(5)" ::: "memory");
        __builtin_amdgcn_s_barrier();
        asm volatile("" ::: "memory");    // keep LDS reads below the barrier

        if (tid < P * OUT) {              // 112 threads: one (plane, out-row) each
            const int p  = tid / 7;
            const int i  = tid - p * 7;
            const int Lh = LH[t];
            const int V  = (7 * Lh + 1) >> 1;
            const int PS = 4 * V;         // packed plane stride in floats (FIXED)

            int th = i * Lh;
            int r1 = th / 7;
            int r3 = (th + Lh + 6) / 7 - 1;
            int r2 = min(r1 + 1, r3);

            const float*  pb = (const float*)&buf[t & 1][0] + p * PS;
            const float2* a  = (const float2*)(pb + r1 * WMAX);
            const float2* bb = (const float2*)(pb + r2 * WMAX);
            const float2* c  = (const float2*)(pb + r3 * WMAX);

            float vm[WMAX];
            #pragma unroll
            for (int kk = 0; kk < 7; ++kk) {
                float2 x = a[kk], y = bb[kk], z = c[kk];
                vm[2 * kk]     = fmaxf(fmaxf(x.x, y.x), z.x);
                vm[2 * kk + 1] = fmaxf(fmaxf(x.y, y.y), z.y);
            }

            float o[OUT];
            switch (LWv[t]) {
                case  7: hpool< 7>(vm, o); break;
                case  8: hpool< 8>(vm, o); break;
                case  9: hpool< 9>(vm, o); break;
                case 10: hpool<10>(vm, o); break;
                case 11: hpool<11>(vm, o); break;
                case 12: hpool<12>(vm, o); break;
                case 13: hpool<13>(vm, o); break;
                default: hpool<14>(vm, o); break;
            }

            float* os = ostage + tid * OUT;
            #pragma unroll
            for (int j = 0; j < OUT; ++j) os[j] = o[j];
        }

        asm volatile("s_waitcnt lgkmcnt(0)" ::: "memory");
        __builtin_amdgcn_s_barrier();
        asm volatile("" ::: "memory");    // keep ostage reads below the barrier

        if (tid < NOUT / 4) {             // coalesced float4 writeback
            ((float4*)out)[(size_t)(blk + t * G) * (NOUT / 4) + tid] =
                ((const float4*)ostage)[tid];
        }
    }
}

extern "C" void kernel_launch(void* const* d_in, const int* in_sizes, int n_in,
                              void* d_out, int out_size, void* d_ws, size_t ws_size,
                              hipStream_t stream)
{
    const float* rois = (const float*)d_in[0];
    const int*   h    = (const int*)d_in[1];
    const int*   w    = (const int*)d_in[2];
    float*       out  = (float*)d_out;

    roipool_kernel<<<G, 256, 0, stream>>>(rois, h, w, out);
}